// Round 7
// baseline (23.569 us; speedup 1.0000x reference)
//
#include <hip/hip_runtime.h>

// DLGN_VT v5 — two specialized dispatches (de-serialize phases, discriminate overhead):
//   K1 gates:    G[b][f] = sigmoid(30 * x[b] . W_f), f in [0,96). Tiled GEMM from LDS,
//                k-split across 2 thread halves, partial-combine in LDS, store G to d_ws.
//   K2 contract: out[b] = sum_i g1[i] * sum_j g2[j] * dot(V[i][j][kc], g3[kc]) with
//                V held in 32 float4 registers per thread (thread = (j,kchunk)),
//                G tile (16 rows) staged once into LDS, shfl_xor reduce, direct store.
// No atomics, no memset, overwrite out.

#define BETA 30.0f

__device__ __forceinline__ float f4c(const float4 v, int c) {
    // compile-time c after full unroll -> folds to a register pick
    return c == 0 ? v.x : (c == 1 ? v.y : (c == 2 ? v.z : v.w));
}

// ---------------- K1: gates ----------------
__global__ __launch_bounds__(256, 2) void gates_v5_kernel(
    const float* __restrict__ x,
    const float* __restrict__ W1,
    const float* __restrict__ W2,
    const float* __restrict__ W3,
    float* __restrict__ G)
{
    __shared__ float Wlds[96 * 132];       // 50688 B
    __shared__ float xlds[16 * 132];       //  8448 B
    __shared__ float Pscr[2][128 * 13];    // 13312 B  -> total 72448 B (2 blocks/CU)

    const int t  = threadIdx.x;
    const int b0 = blockIdx.x * 16;

    // stage W rows 0..95 + x rows 96..111 : 3584 float4, 14/thread, coalesced
#pragma unroll
    for (int r = 0; r < 14; ++r) {
        const int idx  = r * 256 + t;
        const int row  = idx >> 5;
        const int col4 = idx & 31;
        if (row < 96) {
            const float* Wr = (row < 32) ? (W1 + row * 128)
                            : (row < 64) ? (W2 + (row - 32) * 128)
                                         : (W3 + (row - 64) * 128);
            *(float4*)&Wlds[row * 132 + col4 * 4] = ((const float4*)Wr)[col4];
        } else {
            *(float4*)&xlds[(row - 96) * 132 + col4 * 4] =
                ((const float4*)(x + (size_t)(b0 + row - 96) * 128))[col4];
        }
    }
    __syncthreads();

    // thread -> (ks = k-half, bp -> rows 2bp..2bp+1, fg; f = fg + 16*ff)
    {
        const int ks  = t >> 7;
        const int sub = t & 127;
        const int bp  = sub & 7;
        const int fg  = sub >> 3;
        const float* xr0 = &xlds[(2 * bp + 0) * 132];
        const float* xr1 = &xlds[(2 * bp + 1) * 132];
        const float* wb  = &Wlds[fg * 132];
        float acc0[6] = {0.f,0.f,0.f,0.f,0.f,0.f};
        float acc1[6] = {0.f,0.f,0.f,0.f,0.f,0.f};
#pragma unroll
        for (int cc = 0; cc < 16; ++cc) {
            const int c4 = (ks * 16 + cc) * 4;
            const float4 xv0 = *(const float4*)&xr0[c4];
            const float4 xv1 = *(const float4*)&xr1[c4];
#pragma unroll
            for (int ff = 0; ff < 6; ++ff) {
                const float4 wv = *(const float4*)&wb[ff * 2112 + c4];  // row fg+16ff
                acc0[ff] = fmaf(xv0.x, wv.x, acc0[ff]);
                acc0[ff] = fmaf(xv0.y, wv.y, acc0[ff]);
                acc0[ff] = fmaf(xv0.z, wv.z, acc0[ff]);
                acc0[ff] = fmaf(xv0.w, wv.w, acc0[ff]);
                acc1[ff] = fmaf(xv1.x, wv.x, acc1[ff]);
                acc1[ff] = fmaf(xv1.y, wv.y, acc1[ff]);
                acc1[ff] = fmaf(xv1.z, wv.z, acc1[ff]);
                acc1[ff] = fmaf(xv1.w, wv.w, acc1[ff]);
            }
        }
        float* ps = &Pscr[ks][(bp * 16 + fg) * 13];
#pragma unroll
        for (int ff = 0; ff < 6; ++ff) { ps[ff] = acc0[ff]; ps[6 + ff] = acc1[ff]; }
    }
    __syncthreads();

    // combine k-halves + sigmoid + store G in (b,f)-linear order, 6/thread, coalesced
#pragma unroll
    for (int r = 0; r < 6; ++r) {
        const int o = t * 6 + r;            // [0,1536)
        const int b = o / 96;
        const int f = o - b * 96;
        const int idx = ((b >> 1) * 16 + (f & 15)) * 13 + (b & 1) * 6 + (f >> 4);
        const float a = Pscr[0][idx] + Pscr[1][idx];
        G[(size_t)(b0 + b) * 96 + f] = 1.0f / (1.0f + __expf(-BETA * a));
    }
}

// ---------------- K2: contraction ----------------
__global__ __launch_bounds__(256, 2) void contract_v5_kernel(
    const float* __restrict__ G,
    const float* __restrict__ V,
    float* __restrict__ out)
{
    __shared__ float Gs[16][100];
    __shared__ float red[4][16];

    const int t  = threadIdx.x;
    const int b0 = blockIdx.x * 16;

    // V[i][j][kchunk] for all i -> 32 float4 regs; thread = (j = t>>3, c2 = t&7)
    const float4* V4 = (const float4*)V;
    float4 v[32];
#pragma unroll
    for (int i = 0; i < 32; ++i) v[i] = V4[i * 256 + t];   // coalesced, disjoint

    // stage G tile (16 x 96), 6 floats/thread, contiguous global reads
#pragma unroll
    for (int q = 0; q < 6; ++q) {
        const int o = t * 6 + q;            // [0,1536)
        const int b = o / 96;
        const int f = o - b * 96;
        Gs[b][f] = G[(size_t)b0 * 96 + o];
    }
    __syncthreads();

    const int j  = t >> 3;
    const int c2 = t & 7;
    const int w  = t >> 6;
    const int l  = t & 63;

    for (int b = 0; b < 16; ++b) {
        const float4* Gr = (const float4*)&Gs[b][0];
        float4 g1r[8];
#pragma unroll
        for (int c = 0; c < 8; ++c) g1r[c] = Gr[c];             // uniform broadcast
        const float4 g3r = *(const float4*)&Gs[b][64 + c2 * 4]; // 8 addrs, 8 banks
        const float  g2s = Gs[b][32 + j];                       // 32 banks

        float s = 0.f;
#pragma unroll
        for (int i = 0; i < 32; ++i) {
            float d4 = v[i].x * g3r.x;
            d4 = fmaf(v[i].y, g3r.y, d4);
            d4 = fmaf(v[i].z, g3r.z, d4);
            d4 = fmaf(v[i].w, g3r.w, d4);
            s = fmaf(f4c(g1r[i >> 2], i & 3), d4, s);
        }
        float p = s * g2s;
        p += __shfl_xor(p, 1);
        p += __shfl_xor(p, 2);
        p += __shfl_xor(p, 4);
        p += __shfl_xor(p, 8);
        p += __shfl_xor(p, 16);
        p += __shfl_xor(p, 32);
        if (l == 0) red[w][b] = p;
    }
    __syncthreads();

    if (t < 16) out[b0 + t] = red[0][t] + red[1][t] + red[2][t] + red[3][t];
}

extern "C" void kernel_launch(void* const* d_in, const int* in_sizes, int n_in,
                              void* d_out, int out_size, void* d_ws, size_t ws_size,
                              hipStream_t stream) {
    const float* x  = (const float*)d_in[0];
    const float* W1 = (const float*)d_in[1];
    const float* W2 = (const float*)d_in[2];
    const float* W3 = (const float*)d_in[3];
    const float* V  = (const float*)d_in[4];
    float* out = (float*)d_out;
    float* G   = (float*)d_ws;   // 4096*96*4 = 1.5 MB scratch

    gates_v5_kernel<<<dim3(256), dim3(256), 0, stream>>>(x, W1, W2, W3, G);
    contract_v5_kernel<<<dim3(256), dim3(256), 0, stream>>>(G, V, out);
}

// Round 8
// 18.673 us; speedup vs baseline: 1.2622x; 1.2622x over previous
//
#include <hip/hip_runtime.h>

// DLGN_VT v6 — two lean dispatches, occupancy-first:
//   K1 gates: 512 blocks x 256 thr, 8 rows/block, k-quarter split -> ALL 4 waves active.
//     thread=(ks=t>>6, bp, fg): 2-row x 6-feature register tile, 8 LDS b128 reads/48 FMA.
//     Partials -> Pscr[4][64*13] (pad 13, 2-way max), combine+sigmoid -> G coalesced.
//   K2 contract: 512 blocks x 256 thr, 8 rows/block, thread=(j=t>>3, c2=t&7).
//     V[i][j][4c2..] in 32 float4 regs (coalesced, disjoint). Per b: u4 = sum_i g1_i*v[i]
//     (i-first: 128+5 FMA vs 160), s = dot4(u4,g3), p = s*g2; shfl_xor reduce -> out.
// No atomics, no memset; G (1.5 MB) in d_ws.

#define BETA 30.0f

__device__ __forceinline__ float f4c(const float4 v, int c) {
    // compile-time c after full unroll -> folds to a register pick
    return c == 0 ? v.x : (c == 1 ? v.y : (c == 2 ? v.z : v.w));
}

// ---------------- K1: gates ----------------
__global__ __launch_bounds__(256, 2) void gates_v6_kernel(
    const float* __restrict__ x,
    const float* __restrict__ W1,
    const float* __restrict__ W2,
    const float* __restrict__ W3,
    float* __restrict__ G)
{
    __shared__ float Wlds[96 * 132];    // 50688 B
    __shared__ float xlds[8 * 132];     //  4224 B
    __shared__ float Pscr[4][64 * 13];  // 13312 B  -> total 68224 B (2 blocks/CU)

    const int t  = threadIdx.x;
    const int b0 = blockIdx.x * 8;

    // stage W rows 0..95 + x rows 96..103 : 3328 float4 = 13/thread, coalesced
#pragma unroll
    for (int r = 0; r < 13; ++r) {
        const int idx  = r * 256 + t;
        const int row  = idx >> 5;
        const int col4 = idx & 31;
        if (row < 96) {
            const float* Wr = (row < 32) ? (W1 + row * 128)
                            : (row < 64) ? (W2 + (row - 32) * 128)
                                         : (W3 + (row - 64) * 128);
            *(float4*)&Wlds[row * 132 + col4 * 4] = ((const float4*)Wr)[col4];
        } else {
            *(float4*)&xlds[(row - 96) * 132 + col4 * 4] =
                ((const float4*)(x + (size_t)(b0 + row - 96) * 128))[col4];
        }
    }
    __syncthreads();

    // all 4 waves: ks = k-quarter (t>>6); within wave: bp = rows 2bp..2bp+1, fg
    {
        const int ks  = t >> 6;
        const int sub = t & 63;
        const int bp  = sub & 3;
        const int fg  = sub >> 2;          // 0..15, f = fg + 16*ff
        const float* xr0 = &xlds[(2 * bp + 0) * 132];
        const float* xr1 = &xlds[(2 * bp + 1) * 132];
        const float* wb  = &Wlds[fg * 132];
        float acc0[6] = {0.f,0.f,0.f,0.f,0.f,0.f};
        float acc1[6] = {0.f,0.f,0.f,0.f,0.f,0.f};
#pragma unroll
        for (int cc = 0; cc < 8; ++cc) {
            const int c4 = (ks * 8 + cc) * 4;
            const float4 xv0 = *(const float4*)&xr0[c4];
            const float4 xv1 = *(const float4*)&xr1[c4];
#pragma unroll
            for (int ff = 0; ff < 6; ++ff) {
                const float4 wv = *(const float4*)&wb[ff * 2112 + c4];  // row fg+16ff
                acc0[ff] = fmaf(xv0.x, wv.x, acc0[ff]);
                acc0[ff] = fmaf(xv0.y, wv.y, acc0[ff]);
                acc0[ff] = fmaf(xv0.z, wv.z, acc0[ff]);
                acc0[ff] = fmaf(xv0.w, wv.w, acc0[ff]);
                acc1[ff] = fmaf(xv1.x, wv.x, acc1[ff]);
                acc1[ff] = fmaf(xv1.y, wv.y, acc1[ff]);
                acc1[ff] = fmaf(xv1.z, wv.z, acc1[ff]);
                acc1[ff] = fmaf(xv1.w, wv.w, acc1[ff]);
            }
        }
        float* ps = &Pscr[ks][(bp * 16 + fg) * 13];
#pragma unroll
        for (int ff = 0; ff < 6; ++ff) { ps[ff] = acc0[ff]; ps[6 + ff] = acc1[ff]; }
    }
    __syncthreads();

    // combine 4 k-quarters + sigmoid; o = k*256+t -> consecutive lanes write
    // consecutive G addresses (fully coalesced)
#pragma unroll
    for (int k = 0; k < 3; ++k) {
        const int o = k * 256 + t;          // [0,768) = b*96+f
        const int b = o / 96;
        const int f = o - b * 96;
        const int idx = ((b >> 1) * 16 + (f & 15)) * 13 + (b & 1) * 6 + (f >> 4);
        const float a = Pscr[0][idx] + Pscr[1][idx] + Pscr[2][idx] + Pscr[3][idx];
        G[(size_t)(b0 + b) * 96 + f] = 1.0f / (1.0f + __expf(-BETA * a));
    }
}

// ---------------- K2: contraction ----------------
__global__ __launch_bounds__(256, 2) void contract_v6_kernel(
    const float* __restrict__ G,
    const float* __restrict__ V,
    float* __restrict__ out)
{
    __shared__ float Gs[8][100];   // 3200 B (stride 100: conflict-checked)
    __shared__ float red[4][8];

    const int t  = threadIdx.x;
    const int b0 = blockIdx.x * 8;

    // V[i][j][4c2..4c2+3] for all i -> 32 float4 regs; coalesced, disjoint per thread
    const float4* V4 = (const float4*)V;
    float4 v[32];
#pragma unroll
    for (int i = 0; i < 32; ++i) v[i] = V4[i * 256 + t];

    // stage G tile (8 rows x 96 = 192 float4), coalesced
    if (t < 192) {
        const float4 gv = ((const float4*)(G + (size_t)b0 * 96))[t];
        const int b   = t / 24;          // 24 float4 per row
        const int f4i = t - b * 24;
        *(float4*)&Gs[b][f4i * 4] = gv;
    }
    __syncthreads();

    const int j  = t >> 3;   // [0,32)
    const int c2 = t & 7;    // [0,8)
    const int w  = t >> 6;
    const int l  = t & 63;

    for (int b = 0; b < 8; ++b) {          // runtime loop: regs recycle, no hoist-spill
        const float4* Gr = (const float4*)&Gs[b][0];
        float4 g1r[8];
#pragma unroll
        for (int c = 0; c < 8; ++c) g1r[c] = Gr[c];             // uniform broadcast
        const float4 g3r = *(const float4*)&Gs[b][64 + c2 * 4]; // 8 addrs, 32 banks
        const float  g2s = Gs[b][32 + j];                       // 8 addrs, 8 banks

        // i-first: u4 = sum_i g1[i] * v[i]  (128 FMA), then dot4 with g3 (4), scale (1)
        float ux = 0.f, uy = 0.f, uz = 0.f, uw = 0.f;
#pragma unroll
        for (int i = 0; i < 32; ++i) {
            const float g1i = f4c(g1r[i >> 2], i & 3);
            ux = fmaf(g1i, v[i].x, ux);
            uy = fmaf(g1i, v[i].y, uy);
            uz = fmaf(g1i, v[i].z, uz);
            uw = fmaf(g1i, v[i].w, uw);
        }
        float s = ux * g3r.x;
        s = fmaf(uy, g3r.y, s);
        s = fmaf(uz, g3r.z, s);
        s = fmaf(uw, g3r.w, s);
        float p = s * g2s;

        p += __shfl_xor(p, 1);
        p += __shfl_xor(p, 2);
        p += __shfl_xor(p, 4);
        p += __shfl_xor(p, 8);
        p += __shfl_xor(p, 16);
        p += __shfl_xor(p, 32);
        if (l == 0) red[w][b] = p;
    }
    __syncthreads();

    if (t < 8) out[b0 + t] = red[0][t] + red[1][t] + red[2][t] + red[3][t];
}

extern "C" void kernel_launch(void* const* d_in, const int* in_sizes, int n_in,
                              void* d_out, int out_size, void* d_ws, size_t ws_size,
                              hipStream_t stream) {
    const float* x  = (const float*)d_in[0];
    const float* W1 = (const float*)d_in[1];
    const float* W2 = (const float*)d_in[2];
    const float* W3 = (const float*)d_in[3];
    const float* V  = (const float*)d_in[4];
    float* out = (float*)d_out;
    float* G   = (float*)d_ws;   // 4096*96*4 = 1.5 MB scratch

    gates_v6_kernel<<<dim3(512), dim3(256), 0, stream>>>(x, W1, W2, W3, G);
    contract_v6_kernel<<<dim3(512), dim3(256), 0, stream>>>(G, V, out);
}